// Round 9
// baseline (305.156 us; speedup 1.0000x reference)
//
#include <hip/hip_runtime.h>

#define DIM 512
#define NTOK 2304
#define HEADS 8
#define HD 64
#define LN_EPS 1e-5f
#define BNC 2359296   // B*N*C = 2*2304*512
#define QSC 0.18033688011112042f   // 0.125 * log2(e): softmax in exp2 domain

typedef __attribute__((ext_vector_type(8))) short short8;
typedef __attribute__((ext_vector_type(4))) short sh4;
typedef __attribute__((ext_vector_type(4))) float f32x4;

__device__ __forceinline__ short f2bf(float f) {
    union { float f; unsigned u; } x; x.f = f;
    unsigned r = (x.u + 0x7fffu + ((x.u >> 16) & 1u)) >> 16;
    return (short)(r & 0xffffu);
}
__device__ __forceinline__ unsigned fbits(float f) {
    union { float f; unsigned u; } x; x.f = f; return x.u;
}
// async global->LDS DMA, 16B/lane; lds dest = wave-uniform base + lane*16
__device__ __forceinline__ void gl2lds(const short* g, short* l) {
    __builtin_amdgcn_global_load_lds(
        (const __attribute__((address_space(1))) unsigned int*)g,
        (__attribute__((address_space(3))) unsigned int*)l, 16, 0, 0);
}

// -------- fused prep: LN stats (blocks 0..35) + weight transpose (36..227) --------
__global__ void k_prep(const float* __restrict__ x, const float* __restrict__ y,
                       float* __restrict__ mu, float* __restrict__ rs,
                       const float* __restrict__ qv_w, const float* __restrict__ k_w,
                       const float* __restrict__ qv_b, const float* __restrict__ k_b,
                       short* __restrict__ Wt, float* __restrict__ bias) {
    __shared__ __align__(16) float tile[64][65];
    int bx = blockIdx.x, tid = threadIdx.x;
    if (bx < 36) {
        int id = bx * 256 + tid;                // [s][b][n], 9216 total
        int n = id % NTOK;
        int sb = id / NTOK;
        int s = sb >> 1, b = sb & 1;
        const float* src = (s ? y : x) + (size_t)b * DIM * NTOK + n;
        float sum = 0.f, sq = 0.f;
        for (int c = 0; c < DIM; c++) {
            float v = src[(size_t)c * NTOK];
            sum += v; sq += v * v;
        }
        float m = sum * (1.0f / DIM);
        float var = sq * (1.0f / DIM) - m * m;
        mu[id] = m;
        rs[id] = rsqrtf(var + LN_EPS);
        return;
    }
    int idx = bx - 36;
    int jt = idx % 24, ct = idx / 24;
    int j0 = jt * 64, c0 = ct * 64;
    if (ct == 0 && tid < 64) {
        int j = j0 + tid;
        bias[j] = (j < 1024) ? qv_b[j] : k_b[j - 1024];
    }
    for (int slot = tid; slot < 1024; slot += 256) {
        int r = slot >> 4, q = slot & 15;
        int c = c0 + r;
        float4 v;
        if (j0 < 1024) v = *(const float4*)(qv_w + (size_t)c * 1024 + j0 + q * 4);
        else           v = *(const float4*)(k_w  + (size_t)c * 512  + (j0 - 1024) + q * 4);
        tile[r][q*4+0] = v.x; tile[r][q*4+1] = v.y;
        tile[r][q*4+2] = v.z; tile[r][q*4+3] = v.w;
    }
    __syncthreads();
    int jr = tid >> 2, cg = tid & 3;
    short8 o0, o1;
    for (int i = 0; i < 8; i++) o0[i] = f2bf(tile[cg*16+i][jr]);
    for (int i = 0; i < 8; i++) o1[i] = f2bf(tile[cg*16+8+i][jr]);
    short* dst = Wt + (size_t)(j0 + jr) * DIM + c0 + cg * 16;
    *(short8*)dst = o0;
    *(short8*)(dst + 8) = o1;
}

// ---------------- normalize + transpose -> T[s][b][n][c] bf16 ----------------
__global__ void k_normT(const float* __restrict__ x, const float* __restrict__ y,
                        const float* __restrict__ mu, const float* __restrict__ rs,
                        const float* __restrict__ gx, const float* __restrict__ bx,
                        const float* __restrict__ gy, const float* __restrict__ by,
                        short* __restrict__ T) {
    __shared__ __align__(16) float tile[64][65];
    int nt = blockIdx.x, ct = blockIdx.y, sb = blockIdx.z;
    int s = sb >> 1, b = sb & 1;
    int n0 = nt * 64, c0 = ct * 64;
    const float* src = (s ? y : x) + (size_t)b * DIM * NTOK;
    int tid = threadIdx.x;
    for (int slot = tid; slot < 1024; slot += 256) {
        int r = slot >> 4, q = slot & 15;
        const float* p = src + (size_t)(c0 + r) * NTOK + n0 + q * 4;
        float4 v = *(const float4*)p;
        tile[r][q*4+0] = v.x; tile[r][q*4+1] = v.y;
        tile[r][q*4+2] = v.z; tile[r][q*4+3] = v.w;
    }
    __syncthreads();
    const float* g  = s ? gy : gx;
    const float* be = s ? by : bx;
    int nr = tid >> 2, cg = tid & 3;
    int n = n0 + nr;
    float m = mu[sb * NTOK + n], r_ = rs[sb * NTOK + n];
    short8 o0, o1;
    for (int i = 0; i < 8; i++) {
        int c = c0 + cg * 16 + i;
        o0[i] = f2bf((tile[cg*16+i][nr] - m) * r_ * g[c] + be[c]);
    }
    for (int i = 0; i < 8; i++) {
        int c = c0 + cg * 16 + 8 + i;
        o1[i] = f2bf((tile[cg*16+8+i][nr] - m) * r_ * g[c] + be[c]);
    }
    short* dst = T + ((size_t)sb * NTOK + n) * DIM + c0 + cg * 16;
    *(short8*)dst = o0;
    *(short8*)(dst + 8) = o1;
}

// -------- GEMM: 128x128 tile, DMA staging + XOR swizzle, Q pre-scaled --------
__global__ void __launch_bounds__(256)
k_gemm(const short* __restrict__ T, const short* __restrict__ Wt,
       const float* __restrict__ bias, short* __restrict__ QVK) {
    __shared__ __align__(16) short As[128 * 64];
    __shared__ __align__(16) short Bs[128 * 64];
    int n0 = blockIdx.x * 128, j0 = blockIdx.y * 128, sb = blockIdx.z;
    int tid = threadIdx.x;
    int w = tid >> 6, l = tid & 63;
    int wr = w >> 1, wc = w & 1;
    int lrow = l & 15, quad = l >> 4;
    int r_in = (l >> 3) & 7, cc = l & 7;
    int ch = cc ^ r_in;                       // swizzled source chunk
    int sw0 = (quad ^ (lrow & 7)) * 8;        // frag-read chunk offset (shorts)
    const short* Ab = T + (size_t)sb * NTOK * DIM;
    f32x4 acc[4][4] = {};
    for (int kk = 0; kk < 8; kk++) {
        if (kk) __syncthreads();
        for (int inst = 0; inst < 4; inst++) {
            int R = w * 32 + inst * 8 + r_in;
            gl2lds(Ab + (size_t)(n0 + R) * 512 + kk * 64 + ch * 8,
                   &As[(w * 32 + inst * 8) * 64]);
            gl2lds(Wt + (size_t)(j0 + R) * 512 + kk * 64 + ch * 8,
                   &Bs[(w * 32 + inst * 8) * 64]);
        }
        __syncthreads();
        for (int c2 = 0; c2 < 2; c2++) {
            int off = c2 ? (sw0 ^ 32) : sw0;
            short8 af[4], bf[4];
            for (int i = 0; i < 4; i++)
                af[i] = *(const short8*)&As[(wr*64 + i*16 + lrow) * 64 + off];
            for (int j = 0; j < 4; j++)
                bf[j] = *(const short8*)&Bs[(wc*64 + j*16 + lrow) * 64 + off];
            for (int i = 0; i < 4; i++)
                for (int j = 0; j < 4; j++)
                    acc[i][j] = __builtin_amdgcn_mfma_f32_16x16x32_bf16(af[i], bf[j], acc[i][j], 0, 0, 0);
        }
    }
    for (int i = 0; i < 4; i++)
        for (int j = 0; j < 4; j++) {
            int jj = j0 + wc * 64 + j * 16 + lrow;
            float bv = bias[jj];
            float sc = (jj < 512) ? QSC : 1.0f;   // Q pre-scaled into exp2 domain
            for (int reg = 0; reg < 4; reg++) {
                int n = n0 + wr * 64 + i * 16 + quad * 4 + reg;
                QVK[((size_t)sb * NTOK + n) * 1536 + jj] = f2bf((acc[i][j][reg] + bv) * sc);
            }
        }
}

// ---------------- V transpose: VT[sb][j][n] from QVK v-region (coalesced both ways) ----------------
__global__ void k_vtrans(const short* __restrict__ QVK, short* __restrict__ VT) {
    __shared__ short tile[64][65];
    int n0 = blockIdx.x * 64, j0 = blockIdx.y * 64, sb = blockIdx.z;
    int tid = threadIdx.x;
    for (int slot = tid; slot < 512; slot += 256) {
        int r = slot >> 3, seg = slot & 7;
        short8 v = *(const short8*)(QVK + ((size_t)sb * NTOK + n0 + r) * 1536 + 512 + j0 + seg * 8);
        for (int i = 0; i < 8; i++) tile[r][seg * 8 + i] = v[i];
    }
    __syncthreads();
    int jr = tid >> 2, ng = tid & 3;
    short8 o0, o1;
    for (int i = 0; i < 8; i++) o0[i] = tile[ng*16+i][jr];
    for (int i = 0; i < 8; i++) o1[i] = tile[ng*16+8+i][jr];
    short* dst = VT + ((size_t)sb * 512 + j0 + jr) * NTOK + n0 + ng * 16;
    *(short8*)dst = o0;
    *(short8*)(dst + 8) = o1;
}

// ---------------- flash attention: m-split across waves, 128-row supertile ----------------
// Wave w owns m-slice w*32..w*32+31 of each supertile. QK: A=K(slice), B=Q(all 64 n,
// registers) -> S^T[m-within][n]. p=exp2(s), packed to wave-private LDS P[64 n][32 m].
// PV: A=V^T[d][m-slice], B=P -> partial O^T[d][n] per wave; l via ones-MFMA.
// Block reduction of O^T/l across the 4 waves at the end (scratch reuses Ks/Vs/P).
__global__ void __launch_bounds__(256)
k_attn(const short* __restrict__ QVK, const short* __restrict__ VT,
       float* __restrict__ out) {
    __shared__ __align__(16) short smem[26624];   // 53248 B
    short* Ks = smem;                 // [0 .. 8192): 128 rows x 64 shorts (XOR-swizzled)
    short* Vs = smem + 8192;          // [8192 .. 16384): 64 d-rows x 128 shorts (XOR-swizzled)
    // P: per-wave 64 rows x 40 shorts at smem + 16384 + w*2560

    int qt = blockIdx.x;              // 0..35
    int yb = blockIdx.y;              // 0..31
    int br = yb >> 4;
    int b  = (yb >> 3) & 1;
    int h  = yb & 7;
    int tid = threadIdx.x;
    int w = tid >> 6, l = tid & 63;
    int lrow = l & 15, quad = l >> 4;
    int rK = (l >> 3) & 7, cK = l & 7;      // K-DMA: 8 rows x 8 chunks
    int chK = cK ^ rK;
    int rV = l >> 4, cV = l & 15;           // V-DMA: 4 rows x 16 chunks
    int sw0 = (quad ^ (lrow & 7)) * 8;      // ak read pos
    int swV = ((w * 4 + quad) ^ lrow) * 8;  // av read pos (V row&15 == lrow)
    int n0 = qt * 64;
    const short* Qg = QVK + ((size_t)(br * 2 + b) * NTOK) * 1536 + h * 64;           // exp2-scaled Q
    const short* Kg = QVK + ((size_t)((1 - br) * 2 + b) * NTOK) * 1536 + 1024 + h * 64;
    const short* Vg = VT + ((size_t)(br * 2 + b) * 512 + h * 64) * NTOK;
    short* Pw = smem + 16384 + w * 2560;

    // Q fragments straight from global to registers (once per block)
    short8 bq[4][2];
    for (int g = 0; g < 4; g++)
        for (int h2 = 0; h2 < 2; h2++)
            bq[g][h2] = *(const short8*)(Qg + (size_t)(n0 + g * 16 + lrow) * 1536
                                         + h2 * 32 + quad * 8);

    short8 ones;
    for (int i = 0; i < 8; i++) ones[i] = (short)0x3F80;   // bf16 1.0

    f32x4 Oacc[4][4] = {};   // [dg][g] = O^T[dg*16+quad*4+reg][g*16+lane&15] (partial)
    f32x4 lacc[4] = {};      // [g]: rows identical = partial row-sum l

    for (int mt = 0; mt < 18; mt++) {
        int m0 = mt * 128;
        __syncthreads();               // buffers free (prev iter readers done)
        for (int inst = 0; inst < 4; inst++) {
            int R = w * 32 + inst * 8 + rK;                 // K rows (m)
            gl2lds(Kg + (size_t)(m0 + R) * 1536 + chK * 8, &Ks[(w * 32 + inst * 8) * 64]);
            int D = w * 16 + inst * 4 + rV;                 // V rows (d)
            int chV = cV ^ (D & 15);
            gl2lds(Vg + (size_t)D * NTOK + m0 + chV * 8, &Vs[(w * 16 + inst * 4) * 128]);
        }
        __syncthreads();               // drain DMA

        // QK + softmax for this wave's 32 m-rows
        for (int s = 0; s < 2; s++) {
            int krow = (w * 32 + s * 16 + lrow) * 64;
            short8 ak0 = *(const short8*)&Ks[krow + sw0];
            short8 ak1 = *(const short8*)&Ks[krow + (sw0 ^ 32)];
            for (int g = 0; g < 4; g++) {
                f32x4 a = {};
                a = __builtin_amdgcn_mfma_f32_16x16x32_bf16(ak0, bq[g][0], a, 0, 0, 0);
                a = __builtin_amdgcn_mfma_f32_16x16x32_bf16(ak1, bq[g][1], a, 0, 0, 0);
                uint2 pk;
                pk.x = __builtin_amdgcn_perm(fbits(exp2f(a[1])), fbits(exp2f(a[0])), 0x07060302u);
                pk.y = __builtin_amdgcn_perm(fbits(exp2f(a[3])), fbits(exp2f(a[2])), 0x07060302u);
                *(uint2*)&Pw[(g * 16 + lrow) * 40 + s * 16 + quad * 4] = pk;
            }
        }

        // PV + l over this wave's m-slice (same-wave LDS dep, no barrier)
        short8 av[4];
        for (int dg = 0; dg < 4; dg++)
            av[dg] = *(const short8*)&Vs[(dg * 16 + lrow) * 128 + swV];
        for (int g = 0; g < 4; g++) {
            short8 ap = *(const short8*)&Pw[(g * 16 + lrow) * 40 + quad * 8];
            lacc[g] = __builtin_amdgcn_mfma_f32_16x16x32_bf16(ones, ap, lacc[g], 0, 0, 0);
            for (int dg = 0; dg < 4; dg++)
                Oacc[dg][g] = __builtin_amdgcn_mfma_f32_16x16x32_bf16(av[dg], ap, Oacc[dg][g], 0, 0, 0);
        }
    }

    // ---- cross-wave reduction: waves 1..3 dump partials, wave 0 sums + stores ----
    __syncthreads();
    if (w > 0) {
        float* dst = (float*)smem + (w - 1) * 4160;   // 16 KB O + 256 B l each
        for (int dg = 0; dg < 4; dg++)
            for (int g = 0; g < 4; g++)
                *(f32x4*)&dst[(dg * 4 + g) * 256 + l * 4] = Oacc[dg][g];
        if (quad == 0)
            for (int g = 0; g < 4; g++)
                dst[4096 + g * 16 + lrow] = lacc[g][0];
    }
    __syncthreads();
    if (w == 0) {
        for (int v = 0; v < 3; v++) {
            float* src = (float*)smem + v * 4160;
            for (int dg = 0; dg < 4; dg++)
                for (int g = 0; g < 4; g++)
                    Oacc[dg][g] += *(f32x4*)&src[(dg * 4 + g) * 256 + l * 4];
        }
        float linv[4];
        for (int g = 0; g < 4; g++) {
            float ls = lacc[g][0];
            for (int v = 0; v < 3; v++)
                ls += ((float*)smem)[v * 4160 + 4096 + g * 16 + lrow];
            linv[g] = 1.f / ls;
        }
        for (int dg = 0; dg < 4; dg++)
            for (int g = 0; g < 4; g++) {
                int n = n0 + g * 16 + lrow;
                int d = dg * 16 + quad * 4;
                float4 o;
                o.x = Oacc[dg][g][0] * linv[g];
                o.y = Oacc[dg][g][1] * linv[g];
                o.z = Oacc[dg][g][2] * linv[g];
                o.w = Oacc[dg][g][3] * linv[g];
                if (br == 0)
                    *(float4*)&out[((size_t)b * NTOK + n) * 512 + h * 64 + d] = o;
                else
                    *(float4*)&out[(size_t)BNC + ((size_t)(h * 2 + b) * NTOK + n) * 64 + d] = o;
            }
    }
}

extern "C" void kernel_launch(void* const* d_in, const int* in_sizes, int n_in,
                              void* d_out, int out_size, void* d_ws, size_t ws_size,
                              hipStream_t stream) {
    const float* x     = (const float*)d_in[0];
    const float* y     = (const float*)d_in[1];
    const float* k_w   = (const float*)d_in[2];
    const float* k_b   = (const float*)d_in[3];
    const float* qv_w  = (const float*)d_in[4];
    const float* qv_b  = (const float*)d_in[5];
    const float* lnx_g = (const float*)d_in[6];
    const float* lnx_b = (const float*)d_in[7];
    const float* lny_g = (const float*)d_in[8];
    const float* lny_b = (const float*)d_in[9];
    float* out = (float*)d_out;

    char* ws = (char*)d_ws;
    float* mu   = (float*)ws;                 // 9216 f32
    float* rs   = mu + 9216;                  // 9216 f32
    float* bias = rs + 9216;                  // 1536 f32  (ends at 79872 B)
    short* T    = (short*)(ws + 79872);       // 4,718,592 bf16
    short* Wt   = T + 4718592;                // 786,432 bf16
    short* QVK  = Wt + 786432;                // 14,155,776 bf16
    short* VT   = QVK + 14155776;             // 4,718,592 bf16

    k_prep  <<<228, 256, 0, stream>>>(x, y, mu, rs, qv_w, k_w, qv_b, k_b, Wt, bias);
    k_normT <<<dim3(36, 8, 4), 256, 0, stream>>>(x, y, mu, rs,
                                                 lnx_g, lnx_b, lny_g, lny_b, T);
    k_gemm  <<<dim3(18, 12, 4), 256, 0, stream>>>(T, Wt, bias, QVK);
    k_vtrans<<<dim3(36, 8, 4), 256, 0, stream>>>(QVK, VT);
    k_attn  <<<dim3(36, 32), 256, 0, stream>>>(QVK, VT, out);
}

// Round 10
// 234.136 us; speedup vs baseline: 1.3033x; 1.3033x over previous
//
#include <hip/hip_runtime.h>

#define DIM 512
#define NTOK 2304
#define HEADS 8
#define HD 64
#define LN_EPS 1e-5f
#define BNC 2359296   // B*N*C = 2*2304*512
#define QSC 0.18033688011112042f   // 0.125 * log2(e): softmax in exp2 domain

typedef __attribute__((ext_vector_type(8))) short short8;
typedef __attribute__((ext_vector_type(4))) short sh4;
typedef __attribute__((ext_vector_type(4))) float f32x4;

__device__ __forceinline__ short f2bf(float f) {
    union { float f; unsigned u; } x; x.f = f;
    unsigned r = (x.u + 0x7fffu + ((x.u >> 16) & 1u)) >> 16;
    return (short)(r & 0xffffu);
}
__device__ __forceinline__ unsigned fbits(float f) {
    union { float f; unsigned u; } x; x.f = f; return x.u;
}
// async global->LDS DMA, 16B/lane; lds dest = wave-uniform base + lane*16
__device__ __forceinline__ void gl2lds(const short* g, short* l) {
    __builtin_amdgcn_global_load_lds(
        (const __attribute__((address_space(1))) unsigned int*)g,
        (__attribute__((address_space(3))) unsigned int*)l, 16, 0, 0);
}

// -------- fused prep: LN stats (blocks 0..35) + weight transpose (36..227) --------
__global__ void k_prep(const float* __restrict__ x, const float* __restrict__ y,
                       float* __restrict__ mu, float* __restrict__ rs,
                       const float* __restrict__ qv_w, const float* __restrict__ k_w,
                       const float* __restrict__ qv_b, const float* __restrict__ k_b,
                       short* __restrict__ Wt, float* __restrict__ bias) {
    __shared__ __align__(16) float tile[64][65];
    int bx = blockIdx.x, tid = threadIdx.x;
    if (bx < 36) {
        int id = bx * 256 + tid;                // [s][b][n], 9216 total
        int n = id % NTOK;
        int sb = id / NTOK;
        int s = sb >> 1, b = sb & 1;
        const float* src = (s ? y : x) + (size_t)b * DIM * NTOK + n;
        float sum = 0.f, sq = 0.f;
        for (int c = 0; c < DIM; c++) {
            float v = src[(size_t)c * NTOK];
            sum += v; sq += v * v;
        }
        float m = sum * (1.0f / DIM);
        float var = sq * (1.0f / DIM) - m * m;
        mu[id] = m;
        rs[id] = rsqrtf(var + LN_EPS);
        return;
    }
    int idx = bx - 36;
    int jt = idx % 24, ct = idx / 24;
    int j0 = jt * 64, c0 = ct * 64;
    if (ct == 0 && tid < 64) {
        int j = j0 + tid;
        bias[j] = (j < 1024) ? qv_b[j] : k_b[j - 1024];
    }
    for (int slot = tid; slot < 1024; slot += 256) {
        int r = slot >> 4, q = slot & 15;
        int c = c0 + r;
        float4 v;
        if (j0 < 1024) v = *(const float4*)(qv_w + (size_t)c * 1024 + j0 + q * 4);
        else           v = *(const float4*)(k_w  + (size_t)c * 512  + (j0 - 1024) + q * 4);
        tile[r][q*4+0] = v.x; tile[r][q*4+1] = v.y;
        tile[r][q*4+2] = v.z; tile[r][q*4+3] = v.w;
    }
    __syncthreads();
    int jr = tid >> 2, cg = tid & 3;
    short8 o0, o1;
    for (int i = 0; i < 8; i++) o0[i] = f2bf(tile[cg*16+i][jr]);
    for (int i = 0; i < 8; i++) o1[i] = f2bf(tile[cg*16+8+i][jr]);
    short* dst = Wt + (size_t)(j0 + jr) * DIM + c0 + cg * 16;
    *(short8*)dst = o0;
    *(short8*)(dst + 8) = o1;
}

// ---------------- normalize + transpose -> T[s][b][n][c] bf16 ----------------
__global__ void k_normT(const float* __restrict__ x, const float* __restrict__ y,
                        const float* __restrict__ mu, const float* __restrict__ rs,
                        const float* __restrict__ gx, const float* __restrict__ bx,
                        const float* __restrict__ gy, const float* __restrict__ by,
                        short* __restrict__ T) {
    __shared__ __align__(16) float tile[64][65];
    int nt = blockIdx.x, ct = blockIdx.y, sb = blockIdx.z;
    int s = sb >> 1, b = sb & 1;
    int n0 = nt * 64, c0 = ct * 64;
    const float* src = (s ? y : x) + (size_t)b * DIM * NTOK;
    int tid = threadIdx.x;
    for (int slot = tid; slot < 1024; slot += 256) {
        int r = slot >> 4, q = slot & 15;
        const float* p = src + (size_t)(c0 + r) * NTOK + n0 + q * 4;
        float4 v = *(const float4*)p;
        tile[r][q*4+0] = v.x; tile[r][q*4+1] = v.y;
        tile[r][q*4+2] = v.z; tile[r][q*4+3] = v.w;
    }
    __syncthreads();
    const float* g  = s ? gy : gx;
    const float* be = s ? by : bx;
    int nr = tid >> 2, cg = tid & 3;
    int n = n0 + nr;
    float m = mu[sb * NTOK + n], r_ = rs[sb * NTOK + n];
    short8 o0, o1;
    for (int i = 0; i < 8; i++) {
        int c = c0 + cg * 16 + i;
        o0[i] = f2bf((tile[cg*16+i][nr] - m) * r_ * g[c] + be[c]);
    }
    for (int i = 0; i < 8; i++) {
        int c = c0 + cg * 16 + 8 + i;
        o1[i] = f2bf((tile[cg*16+8+i][nr] - m) * r_ * g[c] + be[c]);
    }
    short* dst = T + ((size_t)sb * NTOK + n) * DIM + c0 + cg * 16;
    *(short8*)dst = o0;
    *(short8*)(dst + 8) = o1;
}

// -------- GEMM: 128x128 tile, DMA staging + XOR swizzle, Q pre-scaled --------
__global__ void __launch_bounds__(256)
k_gemm(const short* __restrict__ T, const short* __restrict__ Wt,
       const float* __restrict__ bias, short* __restrict__ QVK) {
    __shared__ __align__(16) short As[128 * 64];
    __shared__ __align__(16) short Bs[128 * 64];
    int n0 = blockIdx.x * 128, j0 = blockIdx.y * 128, sb = blockIdx.z;
    int tid = threadIdx.x;
    int w = tid >> 6, l = tid & 63;
    int wr = w >> 1, wc = w & 1;
    int lrow = l & 15, quad = l >> 4;
    int r_in = (l >> 3) & 7, cc = l & 7;
    int ch = cc ^ r_in;                       // swizzled source chunk
    int sw0 = (quad ^ (lrow & 7)) * 8;        // frag-read chunk offset (shorts)
    const short* Ab = T + (size_t)sb * NTOK * DIM;
    f32x4 acc[4][4] = {};
    for (int kk = 0; kk < 8; kk++) {
        if (kk) __syncthreads();
        for (int inst = 0; inst < 4; inst++) {
            int R = w * 32 + inst * 8 + r_in;
            gl2lds(Ab + (size_t)(n0 + R) * 512 + kk * 64 + ch * 8,
                   &As[(w * 32 + inst * 8) * 64]);
            gl2lds(Wt + (size_t)(j0 + R) * 512 + kk * 64 + ch * 8,
                   &Bs[(w * 32 + inst * 8) * 64]);
        }
        __syncthreads();
        for (int c2 = 0; c2 < 2; c2++) {
            int off = c2 ? (sw0 ^ 32) : sw0;
            short8 af[4], bf[4];
            for (int i = 0; i < 4; i++)
                af[i] = *(const short8*)&As[(wr*64 + i*16 + lrow) * 64 + off];
            for (int j = 0; j < 4; j++)
                bf[j] = *(const short8*)&Bs[(wc*64 + j*16 + lrow) * 64 + off];
            for (int i = 0; i < 4; i++)
                for (int j = 0; j < 4; j++)
                    acc[i][j] = __builtin_amdgcn_mfma_f32_16x16x32_bf16(af[i], bf[j], acc[i][j], 0, 0, 0);
        }
    }
    for (int i = 0; i < 4; i++)
        for (int j = 0; j < 4; j++) {
            int jj = j0 + wc * 64 + j * 16 + lrow;
            float bv = bias[jj];
            float sc = (jj < 512) ? QSC : 1.0f;   // Q pre-scaled into exp2 domain
            for (int reg = 0; reg < 4; reg++) {
                int n = n0 + wr * 64 + i * 16 + quad * 4 + reg;
                QVK[((size_t)sb * NTOK + n) * 1536 + jj] = f2bf((acc[i][j][reg] + bv) * sc);
            }
        }
}

// ---------------- V transpose: VT[sb][j][n] from QVK v-region (coalesced both ways) ----------------
__global__ void k_vtrans(const short* __restrict__ QVK, short* __restrict__ VT) {
    __shared__ short tile[64][65];
    int n0 = blockIdx.x * 64, j0 = blockIdx.y * 64, sb = blockIdx.z;
    int tid = threadIdx.x;
    for (int slot = tid; slot < 512; slot += 256) {
        int r = slot >> 3, seg = slot & 7;
        short8 v = *(const short8*)(QVK + ((size_t)sb * NTOK + n0 + r) * 1536 + 512 + j0 + seg * 8);
        for (int i = 0; i < 8; i++) tile[r][seg * 8 + i] = v[i];
    }
    __syncthreads();
    int jr = tid >> 2, ng = tid & 3;
    short8 o0, o1;
    for (int i = 0; i < 8; i++) o0[i] = tile[ng*16+i][jr];
    for (int i = 0; i < 8; i++) o1[i] = tile[ng*16+8+i][jr];
    short* dst = VT + ((size_t)sb * 512 + j0 + jr) * NTOK + n0 + ng * 16;
    *(short8*)dst = o0;
    *(short8*)(dst + 8) = o1;
}

// ---------------- flash attention: single-buffer DMA K/V, swizzled LDS ----------------
// QK: A=K rows(m), B=Q rows(n) -> S^T[n=lane&15][m=quad*4+reg]; p=exp2(s) (no max).
// l via ones-MFMA. PV: A=V^T rows(d), B=P rows(n) -> Oacc=O^T[d][n].
// LDS 24 KB (Ks+Vs+Qs, Qs reused as P) -> 6 blocks/CU; VGPR ~52.
__global__ void __launch_bounds__(256)
k_attn(const short* __restrict__ QVK, const short* __restrict__ VT,
       float* __restrict__ out) {
    __shared__ __align__(16) short Ks[64 * 64];
    __shared__ __align__(16) short Vs[64 * 64];
    __shared__ __align__(16) short Qs[64 * 64];   // Q staging; re-used as P (wave-private)
    int qt = blockIdx.x;              // 0..35
    int yb = blockIdx.y;              // 0..31
    int br = yb >> 4;
    int b  = (yb >> 3) & 1;
    int h  = yb & 7;
    int tid = threadIdx.x;
    int w = tid >> 6, l = tid & 63;
    int lrow = l & 15, quad = l >> 4;
    int r_in = (l >> 3) & 7, cc = l & 7;
    int ch = cc ^ r_in;
    int sw0 = (quad ^ (lrow & 7)) * 8;
    int n0 = qt * 64;
    const short* Qg = QVK + ((size_t)(br * 2 + b) * NTOK) * 1536 + h * 64;           // exp2-scaled Q
    const short* Kg = QVK + ((size_t)((1 - br) * 2 + b) * NTOK) * 1536 + 1024 + h * 64;
    const short* Vg = VT + ((size_t)(br * 2 + b) * 512 + h * 64) * NTOK;

    // stage Q (wave w: rows w*16..w*16+15)
    for (int inst = 0; inst < 2; inst++) {
        int R = w * 16 + inst * 8 + r_in;
        gl2lds(Qg + (size_t)(n0 + R) * 1536 + ch * 8, &Qs[(w * 16 + inst * 8) * 64]);
    }
    __syncthreads();
    short8 bq0 = *(const short8*)&Qs[(w * 16 + lrow) * 64 + sw0];
    short8 bq1 = *(const short8*)&Qs[(w * 16 + lrow) * 64 + (sw0 ^ 32)];
    short* Pw = &Qs[w * 16 * 64];     // wave-private P region (16 rows)

    short8 ones;
    for (int i = 0; i < 8; i++) ones[i] = (short)0x3F80;   // bf16 1.0

    f32x4 Oacc[4] = {};
    f32x4 lacc = {};

    for (int mt = 0; mt < 36; mt++) {
        int m0 = mt * 64;
        __syncthreads();              // prev-tile readers done (also covers Q->P reuse)
        for (int inst = 0; inst < 2; inst++) {
            int R = w * 16 + inst * 8 + r_in;
            int Rb = (w * 16 + inst * 8) * 64;
            gl2lds(Kg + (size_t)(m0 + R) * 1536 + ch * 8, &Ks[Rb]);
            gl2lds(Vg + (size_t)R * NTOK + m0 + ch * 8, &Vs[Rb]);
        }
        __syncthreads();              // drain DMA

        for (int sub = 0; sub < 4; sub++) {
            short8 ak0 = *(const short8*)&Ks[(sub * 16 + lrow) * 64 + sw0];
            short8 ak1 = *(const short8*)&Ks[(sub * 16 + lrow) * 64 + (sw0 ^ 32)];
            f32x4 a = {};
            a = __builtin_amdgcn_mfma_f32_16x16x32_bf16(ak0, bq0, a, 0, 0, 0);
            a = __builtin_amdgcn_mfma_f32_16x16x32_bf16(ak1, bq1, a, 0, 0, 0);
            float p0 = exp2f(a[0]), p1 = exp2f(a[1]);
            float p2 = exp2f(a[2]), p3 = exp2f(a[3]);
            uint2 pk;
            pk.x = __builtin_amdgcn_perm(fbits(p1), fbits(p0), 0x07060302u);
            pk.y = __builtin_amdgcn_perm(fbits(p3), fbits(p2), 0x07060302u);
            *(uint2*)&Pw[lrow * 64 + (((2 * sub + (quad >> 1)) ^ (lrow & 7)) * 8) + (quad & 1) * 4] = pk;
        }

        // PV + l-sum: same-wave LDS dep only, no barrier
        short8 ap0 = *(const short8*)&Pw[lrow * 64 + sw0];
        short8 ap1 = *(const short8*)&Pw[lrow * 64 + (sw0 ^ 32)];
        lacc = __builtin_amdgcn_mfma_f32_16x16x32_bf16(ones, ap0, lacc, 0, 0, 0);
        lacc = __builtin_amdgcn_mfma_f32_16x16x32_bf16(ones, ap1, lacc, 0, 0, 0);
        for (int ddt = 0; ddt < 4; ddt++) {
            short8 av0 = *(const short8*)&Vs[(ddt * 16 + lrow) * 64 + sw0];
            short8 av1 = *(const short8*)&Vs[(ddt * 16 + lrow) * 64 + (sw0 ^ 32)];
            Oacc[ddt] = __builtin_amdgcn_mfma_f32_16x16x32_bf16(av0, ap0, Oacc[ddt], 0, 0, 0);
            Oacc[ddt] = __builtin_amdgcn_mfma_f32_16x16x32_bf16(av1, ap1, Oacc[ddt], 0, 0, 0);
        }
    }

    float linv = 1.f / lacc[0];       // all rows of lacc identical (ones A-operand)
    int n = n0 + w * 16 + lrow;
    for (int ddt = 0; ddt < 4; ddt++) {
        float4 o;
        o.x = Oacc[ddt][0] * linv;
        o.y = Oacc[ddt][1] * linv;
        o.z = Oacc[ddt][2] * linv;
        o.w = Oacc[ddt][3] * linv;
        if (br == 0)
            *(float4*)&out[((size_t)b * NTOK + n) * 512 + h * 64 + ddt * 16 + quad * 4] = o;
        else
            *(float4*)&out[(size_t)BNC + ((size_t)(h * 2 + b) * NTOK + n) * 64 + ddt * 16 + quad * 4] = o;
    }
}

extern "C" void kernel_launch(void* const* d_in, const int* in_sizes, int n_in,
                              void* d_out, int out_size, void* d_ws, size_t ws_size,
                              hipStream_t stream) {
    const float* x     = (const float*)d_in[0];
    const float* y     = (const float*)d_in[1];
    const float* k_w   = (const float*)d_in[2];
    const float* k_b   = (const float*)d_in[3];
    const float* qv_w  = (const float*)d_in[4];
    const float* qv_b  = (const float*)d_in[5];
    const float* lnx_g = (const float*)d_in[6];
    const float* lnx_b = (const float*)d_in[7];
    const float* lny_g = (const float*)d_in[8];
    const float* lny_b = (const float*)d_in[9];
    float* out = (float*)d_out;

    char* ws = (char*)d_ws;
    float* mu   = (float*)ws;                 // 9216 f32
    float* rs   = mu + 9216;                  // 9216 f32
    float* bias = rs + 9216;                  // 1536 f32  (ends at 79872 B)
    short* T    = (short*)(ws + 79872);       // 4,718,592 bf16
    short* Wt   = T + 4718592;                // 786,432 bf16
    short* QVK  = Wt + 786432;                // 14,155,776 bf16
    short* VT   = QVK + 14155776;             // 4,718,592 bf16

    k_prep  <<<228, 256, 0, stream>>>(x, y, mu, rs, qv_w, k_w, qv_b, k_b, Wt, bias);
    k_normT <<<dim3(36, 8, 4), 256, 0, stream>>>(x, y, mu, rs,
                                                 lnx_g, lnx_b, lny_g, lny_b, T);
    k_gemm  <<<dim3(18, 12, 4), 256, 0, stream>>>(T, Wt, bias, QVK);
    k_vtrans<<<dim3(36, 8, 4), 256, 0, stream>>>(QVK, VT);
    k_attn  <<<dim3(36, 32), 256, 0, stream>>>(QVK, VT, out);
}

// Round 11
// 205.591 us; speedup vs baseline: 1.4843x; 1.1388x over previous
//
#include <hip/hip_runtime.h>

#define DIM 512
#define NTOK 2304
#define HEADS 8
#define HD 64
#define LN_EPS 1e-5f
#define BNC 2359296   // B*N*C = 2*2304*512
#define QSC 0.18033688011112042f   // 0.125 * log2(e): softmax in exp2 domain

typedef __attribute__((ext_vector_type(8))) short short8;
typedef __attribute__((ext_vector_type(4))) short sh4;
typedef __attribute__((ext_vector_type(4))) float f32x4;

__device__ __forceinline__ short f2bf(float f) {
    union { float f; unsigned u; } x; x.f = f;
    unsigned r = (x.u + 0x7fffu + ((x.u >> 16) & 1u)) >> 16;
    return (short)(r & 0xffffu);
}
__device__ __forceinline__ unsigned fbits(float f) {
    union { float f; unsigned u; } x; x.f = f; return x.u;
}
// async global->LDS DMA, 16B/lane; lds dest = wave-uniform base + lane*16
__device__ __forceinline__ void gl2lds(const short* g, short* l) {
    __builtin_amdgcn_global_load_lds(
        (const __attribute__((address_space(1))) unsigned int*)g,
        (__attribute__((address_space(3))) unsigned int*)l, 16, 0, 0);
}

// -------- fused prep: LN stats (blocks 0..143, 4-way c-split) + weight transpose (144..335) --------
__global__ void k_prep(const float* __restrict__ x, const float* __restrict__ y,
                       float* __restrict__ mu, float* __restrict__ rs,
                       const float* __restrict__ qv_w, const float* __restrict__ k_w,
                       const float* __restrict__ qv_b, const float* __restrict__ k_b,
                       short* __restrict__ Wt, float* __restrict__ bias) {
    __shared__ __align__(16) float tile[64][65];
    __shared__ float pS[4][64], pQ[4][64];
    int bx = blockIdx.x, tid = threadIdx.x;
    if (bx < 144) {
        int nt = bx % 36, sb = bx / 36;
        int nl = tid & 63, part = tid >> 6;
        int n = nt * 64 + nl;
        int s = sb >> 1, b = sb & 1;
        const float* src = (s ? y : x) + (size_t)b * DIM * NTOK + n;
        float sum = 0.f, sq = 0.f;
        for (int c = part * 128; c < part * 128 + 128; c++) {
            float v = src[(size_t)c * NTOK];
            sum += v; sq += v * v;
        }
        pS[part][nl] = sum; pQ[part][nl] = sq;
        __syncthreads();
        if (tid < 64) {
            float ts = pS[0][tid] + pS[1][tid] + pS[2][tid] + pS[3][tid];
            float tq = pQ[0][tid] + pQ[1][tid] + pQ[2][tid] + pQ[3][tid];
            float m = ts * (1.0f / DIM);
            float var = tq * (1.0f / DIM) - m * m;
            mu[sb * NTOK + nt * 64 + tid] = m;
            rs[sb * NTOK + nt * 64 + tid] = rsqrtf(var + LN_EPS);
        }
        return;
    }
    int idx = bx - 144;
    int jt = idx % 24, ct = idx / 24;
    int j0 = jt * 64, c0 = ct * 64;
    if (ct == 0 && tid < 64) {
        int j = j0 + tid;
        bias[j] = (j < 1024) ? qv_b[j] : k_b[j - 1024];
    }
    for (int slot = tid; slot < 1024; slot += 256) {
        int r = slot >> 4, q = slot & 15;
        int c = c0 + r;
        float4 v;
        if (j0 < 1024) v = *(const float4*)(qv_w + (size_t)c * 1024 + j0 + q * 4);
        else           v = *(const float4*)(k_w  + (size_t)c * 512  + (j0 - 1024) + q * 4);
        tile[r][q*4+0] = v.x; tile[r][q*4+1] = v.y;
        tile[r][q*4+2] = v.z; tile[r][q*4+3] = v.w;
    }
    __syncthreads();
    int jr = tid >> 2, cg = tid & 3;
    short8 o0, o1;
    for (int i = 0; i < 8; i++) o0[i] = f2bf(tile[cg*16+i][jr]);
    for (int i = 0; i < 8; i++) o1[i] = f2bf(tile[cg*16+8+i][jr]);
    short* dst = Wt + (size_t)(j0 + jr) * DIM + c0 + cg * 16;
    *(short8*)dst = o0;
    *(short8*)(dst + 8) = o1;
}

// ---------------- normalize + transpose -> T[s][b][n][c] bf16 ----------------
__global__ void k_normT(const float* __restrict__ x, const float* __restrict__ y,
                        const float* __restrict__ mu, const float* __restrict__ rs,
                        const float* __restrict__ gx, const float* __restrict__ bx,
                        const float* __restrict__ gy, const float* __restrict__ by,
                        short* __restrict__ T) {
    __shared__ __align__(16) float tile[64][65];
    int nt = blockIdx.x, ct = blockIdx.y, sb = blockIdx.z;
    int s = sb >> 1, b = sb & 1;
    int n0 = nt * 64, c0 = ct * 64;
    const float* src = (s ? y : x) + (size_t)b * DIM * NTOK;
    int tid = threadIdx.x;
    for (int slot = tid; slot < 1024; slot += 256) {
        int r = slot >> 4, q = slot & 15;
        const float* p = src + (size_t)(c0 + r) * NTOK + n0 + q * 4;
        float4 v = *(const float4*)p;
        tile[r][q*4+0] = v.x; tile[r][q*4+1] = v.y;
        tile[r][q*4+2] = v.z; tile[r][q*4+3] = v.w;
    }
    __syncthreads();
    const float* g  = s ? gy : gx;
    const float* be = s ? by : bx;
    int nr = tid >> 2, cg = tid & 3;
    int n = n0 + nr;
    float m = mu[sb * NTOK + n], r_ = rs[sb * NTOK + n];
    short8 o0, o1;
    for (int i = 0; i < 8; i++) {
        int c = c0 + cg * 16 + i;
        o0[i] = f2bf((tile[cg*16+i][nr] - m) * r_ * g[c] + be[c]);
    }
    for (int i = 0; i < 8; i++) {
        int c = c0 + cg * 16 + 8 + i;
        o1[i] = f2bf((tile[cg*16+8+i][nr] - m) * r_ * g[c] + be[c]);
    }
    short* dst = T + ((size_t)sb * NTOK + n) * DIM + c0 + cg * 16;
    *(short8*)dst = o0;
    *(short8*)(dst + 8) = o1;
}

// -------- GEMM: 128x128 tile, DMA staging + XOR swizzle, Q pre-scaled --------
// V-region blocks (j0 in [512,1024)) transpose their tile via LDS and write VT
// directly (coalesced row stores) -- replaces the separate k_vtrans kernel.
__global__ void __launch_bounds__(256)
k_gemm(const short* __restrict__ T, const short* __restrict__ Wt,
       const float* __restrict__ bias, short* __restrict__ QVK,
       short* __restrict__ VT) {
    __shared__ __align__(16) short smem[2 * 128 * 64];
    short* As = smem;
    short* Bs = smem + 128 * 64;
    int n0 = blockIdx.x * 128, j0 = blockIdx.y * 128, sb = blockIdx.z;
    int tid = threadIdx.x;
    int w = tid >> 6, l = tid & 63;
    int wr = w >> 1, wc = w & 1;
    int lrow = l & 15, quad = l >> 4;
    int r_in = (l >> 3) & 7, cc = l & 7;
    int ch = cc ^ r_in;                       // swizzled source chunk
    int sw0 = (quad ^ (lrow & 7)) * 8;        // frag-read chunk offset (shorts)
    const short* Ab = T + (size_t)sb * NTOK * DIM;
    f32x4 acc[4][4] = {};
    for (int kk = 0; kk < 8; kk++) {
        if (kk) __syncthreads();
        for (int inst = 0; inst < 4; inst++) {
            int R = w * 32 + inst * 8 + r_in;
            gl2lds(Ab + (size_t)(n0 + R) * 512 + kk * 64 + ch * 8,
                   &As[(w * 32 + inst * 8) * 64]);
            gl2lds(Wt + (size_t)(j0 + R) * 512 + kk * 64 + ch * 8,
                   &Bs[(w * 32 + inst * 8) * 64]);
        }
        __syncthreads();
        for (int c2 = 0; c2 < 2; c2++) {
            int off = c2 ? (sw0 ^ 32) : sw0;
            short8 af[4], bf[4];
            for (int i = 0; i < 4; i++)
                af[i] = *(const short8*)&As[(wr*64 + i*16 + lrow) * 64 + off];
            for (int j = 0; j < 4; j++)
                bf[j] = *(const short8*)&Bs[(wc*64 + j*16 + lrow) * 64 + off];
            for (int i = 0; i < 4; i++)
                for (int j = 0; j < 4; j++)
                    acc[i][j] = __builtin_amdgcn_mfma_f32_16x16x32_bf16(af[i], bf[j], acc[i][j], 0, 0, 0);
        }
    }
    if (j0 >= 512 && j0 < 1024) {
        // ---- V block: transpose tile in LDS (reuse As+Bs as 128x128), write VT ----
        __syncthreads();               // main-loop LDS readers done
        for (int i = 0; i < 4; i++)
            for (int j = 0; j < 4; j++) {
                int jloc = wc * 64 + j * 16 + lrow;           // V row (within tile)
                float bv = bias[j0 + jloc];
                int nloc = wr * 64 + i * 16 + quad * 4;       // n col
                int c8 = nloc >> 3, half = (nloc >> 2) & 1;
                sh4 pk;
                for (int reg = 0; reg < 4; reg++) pk[reg] = f2bf(acc[i][j][reg] + bv);
                *(sh4*)&smem[jloc * 128 + ((c8 ^ (jloc & 15)) * 8) + half * 4] = pk;
            }
        __syncthreads();
        for (int slot = tid; slot < 2048; slot += 256) {
            int row = slot >> 4, seg = slot & 15;
            short8 v = *(const short8*)&smem[row * 128 + ((seg ^ (row & 15)) * 8)];
            *(short8*)(VT + ((size_t)sb * 512 + (j0 - 512) + row) * NTOK + n0 + seg * 8) = v;
        }
    } else {
        for (int i = 0; i < 4; i++)
            for (int j = 0; j < 4; j++) {
                int jj = j0 + wc * 64 + j * 16 + lrow;
                float bv = bias[jj];
                float sc = (jj < 512) ? QSC : 1.0f;   // Q pre-scaled into exp2 domain
                for (int reg = 0; reg < 4; reg++) {
                    int n = n0 + wr * 64 + i * 16 + quad * 4 + reg;
                    QVK[((size_t)sb * NTOK + n) * 1536 + jj] = f2bf((acc[i][j][reg] + bv) * sc);
                }
            }
    }
}

// ---------------- flash attention: single-buffer DMA K/V, swizzled LDS ----------------
// QK: A=K rows(m), B=Q rows(n) -> S^T[n=lane&15][m=quad*4+reg]; p=exp2(s) (no max).
// l via ones-MFMA. PV: A=V^T rows(d), B=P rows(n) -> Oacc=O^T[d][n].
// LDS 24 KB (Ks+Vs+Qs, Qs reused as P); VGPR ~44.
__global__ void __launch_bounds__(256)
k_attn(const short* __restrict__ QVK, const short* __restrict__ VT,
       float* __restrict__ out) {
    __shared__ __align__(16) short Ks[64 * 64];
    __shared__ __align__(16) short Vs[64 * 64];
    __shared__ __align__(16) short Qs[64 * 64];   // Q staging; re-used as P (wave-private)
    int qt = blockIdx.x;              // 0..35
    int yb = blockIdx.y;              // 0..31
    int br = yb >> 4;
    int b  = (yb >> 3) & 1;
    int h  = yb & 7;
    int tid = threadIdx.x;
    int w = tid >> 6, l = tid & 63;
    int lrow = l & 15, quad = l >> 4;
    int r_in = (l >> 3) & 7, cc = l & 7;
    int ch = cc ^ r_in;
    int sw0 = (quad ^ (lrow & 7)) * 8;
    int n0 = qt * 64;
    const short* Qg = QVK + ((size_t)(br * 2 + b) * NTOK) * 1536 + h * 64;           // exp2-scaled Q
    const short* Kg = QVK + ((size_t)((1 - br) * 2 + b) * NTOK) * 1536 + 1024 + h * 64;
    const short* Vg = VT + ((size_t)(br * 2 + b) * 512 + h * 64) * NTOK;

    // stage Q (wave w: rows w*16..w*16+15)
    for (int inst = 0; inst < 2; inst++) {
        int R = w * 16 + inst * 8 + r_in;
        gl2lds(Qg + (size_t)(n0 + R) * 1536 + ch * 8, &Qs[(w * 16 + inst * 8) * 64]);
    }
    __syncthreads();
    short8 bq0 = *(const short8*)&Qs[(w * 16 + lrow) * 64 + sw0];
    short8 bq1 = *(const short8*)&Qs[(w * 16 + lrow) * 64 + (sw0 ^ 32)];
    short* Pw = &Qs[w * 16 * 64];     // wave-private P region (16 rows)

    short8 ones;
    for (int i = 0; i < 8; i++) ones[i] = (short)0x3F80;   // bf16 1.0

    f32x4 Oacc[4] = {};
    f32x4 lacc = {};

    for (int mt = 0; mt < 36; mt++) {
        int m0 = mt * 64;
        __syncthreads();              // prev-tile readers done (also covers Q->P reuse)
        for (int inst = 0; inst < 2; inst++) {
            int R = w * 16 + inst * 8 + r_in;
            int Rb = (w * 16 + inst * 8) * 64;
            gl2lds(Kg + (size_t)(m0 + R) * 1536 + ch * 8, &Ks[Rb]);
            gl2lds(Vg + (size_t)R * NTOK + m0 + ch * 8, &Vs[Rb]);
        }
        __syncthreads();              // drain DMA

        for (int sub = 0; sub < 4; sub++) {
            short8 ak0 = *(const short8*)&Ks[(sub * 16 + lrow) * 64 + sw0];
            short8 ak1 = *(const short8*)&Ks[(sub * 16 + lrow) * 64 + (sw0 ^ 32)];
            f32x4 a = {};
            a = __builtin_amdgcn_mfma_f32_16x16x32_bf16(ak0, bq0, a, 0, 0, 0);
            a = __builtin_amdgcn_mfma_f32_16x16x32_bf16(ak1, bq1, a, 0, 0, 0);
            float p0 = exp2f(a[0]), p1 = exp2f(a[1]);
            float p2 = exp2f(a[2]), p3 = exp2f(a[3]);
            uint2 pk;
            pk.x = __builtin_amdgcn_perm(fbits(p1), fbits(p0), 0x07060302u);
            pk.y = __builtin_amdgcn_perm(fbits(p3), fbits(p2), 0x07060302u);
            *(uint2*)&Pw[lrow * 64 + (((2 * sub + (quad >> 1)) ^ (lrow & 7)) * 8) + (quad & 1) * 4] = pk;
        }

        // PV + l-sum: same-wave LDS dep only, no barrier
        short8 ap0 = *(const short8*)&Pw[lrow * 64 + sw0];
        short8 ap1 = *(const short8*)&Pw[lrow * 64 + (sw0 ^ 32)];
        lacc = __builtin_amdgcn_mfma_f32_16x16x32_bf16(ones, ap0, lacc, 0, 0, 0);
        lacc = __builtin_amdgcn_mfma_f32_16x16x32_bf16(ones, ap1, lacc, 0, 0, 0);
        for (int ddt = 0; ddt < 4; ddt++) {
            short8 av0 = *(const short8*)&Vs[(ddt * 16 + lrow) * 64 + sw0];
            short8 av1 = *(const short8*)&Vs[(ddt * 16 + lrow) * 64 + (sw0 ^ 32)];
            Oacc[ddt] = __builtin_amdgcn_mfma_f32_16x16x32_bf16(av0, ap0, Oacc[ddt], 0, 0, 0);
            Oacc[ddt] = __builtin_amdgcn_mfma_f32_16x16x32_bf16(av1, ap1, Oacc[ddt], 0, 0, 0);
        }
    }

    float linv = 1.f / lacc[0];       // all rows of lacc identical (ones A-operand)
    int n = n0 + w * 16 + lrow;
    for (int ddt = 0; ddt < 4; ddt++) {
        float4 o;
        o.x = Oacc[ddt][0] * linv;
        o.y = Oacc[ddt][1] * linv;
        o.z = Oacc[ddt][2] * linv;
        o.w = Oacc[ddt][3] * linv;
        if (br == 0)
            *(float4*)&out[((size_t)b * NTOK + n) * 512 + h * 64 + ddt * 16 + quad * 4] = o;
        else
            *(float4*)&out[(size_t)BNC + ((size_t)(h * 2 + b) * NTOK + n) * 64 + ddt * 16 + quad * 4] = o;
    }
}

extern "C" void kernel_launch(void* const* d_in, const int* in_sizes, int n_in,
                              void* d_out, int out_size, void* d_ws, size_t ws_size,
                              hipStream_t stream) {
    const float* x     = (const float*)d_in[0];
    const float* y     = (const float*)d_in[1];
    const float* k_w   = (const float*)d_in[2];
    const float* k_b   = (const float*)d_in[3];
    const float* qv_w  = (const float*)d_in[4];
    const float* qv_b  = (const float*)d_in[5];
    const float* lnx_g = (const float*)d_in[6];
    const float* lnx_b = (const float*)d_in[7];
    const float* lny_g = (const float*)d_in[8];
    const float* lny_b = (const float*)d_in[9];
    float* out = (float*)d_out;

    char* ws = (char*)d_ws;
    float* mu   = (float*)ws;                 // 9216 f32
    float* rs   = mu + 9216;                  // 9216 f32
    float* bias = rs + 9216;                  // 1536 f32  (ends at 79872 B)
    short* T    = (short*)(ws + 79872);       // 4,718,592 bf16
    short* Wt   = T + 4718592;                // 786,432 bf16
    short* QVK  = Wt + 786432;                // 14,155,776 bf16 (V region unused)
    short* VT   = QVK + 14155776;             // 4,718,592 bf16

    k_prep  <<<336, 256, 0, stream>>>(x, y, mu, rs, qv_w, k_w, qv_b, k_b, Wt, bias);
    k_normT <<<dim3(36, 8, 4), 256, 0, stream>>>(x, y, mu, rs,
                                                 lnx_g, lnx_b, lny_g, lny_b, T);
    k_gemm  <<<dim3(18, 12, 4), 256, 0, stream>>>(T, Wt, bias, QVK, VT);
    k_attn  <<<dim3(36, 32), 256, 0, stream>>>(QVK, VT, out);
}